// Round 1
// 2768.456 us; speedup vs baseline: 1.0697x; 1.0697x over previous
//
#include <hip/hip_runtime.h>

#define HH   51
#define H4   204
#define TSEQ 2048
#define FUT  64
#define TT   (TSEQ + FUT)   // 2112
#define RPB  16             // batch rows per block (2 blocks/CU)
#define NTH  1024           // 16 waves: 13 compute + emit + x-prefetch + 1 idle
#define HSTR 80             // halfs per hbuf row (160 B stride)

typedef _Float16 h8 __attribute__((ext_vector_type(8)));
typedef float    f4 __attribute__((ext_vector_type(4)));

#define LOG2E 1.44269504f
#define MFMA(a, b, c) __builtin_amdgcn_mfma_f32_16x16x32_f16(a, b, c, 0, 0, 0)

// Full LSTM-cell nonlinearity from gate pre-activations g = {i,f,g,o}.
// Pairwise-reciprocal trick: 5 exp2 + 3 rcp (vs naive 5+5). Gate preacts are
// bounded (|z| <~ 8 from weight init), so A*B / G*C cannot overflow.
__device__ __forceinline__ void act_cell(const f4 g, float cin, float* cout, float* hout) {
    const float ei = __builtin_amdgcn_exp2f(-LOG2E * g[0]);
    const float ef = __builtin_amdgcn_exp2f(-LOG2E * g[1]);
    const float eg = __builtin_amdgcn_exp2f(-2.0f * LOG2E * g[2]);
    const float eo = __builtin_amdgcn_exp2f(-LOG2E * g[3]);
    const float A = 1.0f + ei, B = 1.0f + ef, G = 1.0f + eg, C = 1.0f + eo;
    const float rAB = __builtin_amdgcn_rcpf(A * B);
    const float ig = rAB * B;                                 // sigmoid(g0) = 1/A
    const float fg = rAB * A;                                 // sigmoid(g1) = 1/B
    const float rGC = __builtin_amdgcn_rcpf(G * C);
    const float og = rGC * G;                                 // sigmoid(g3) = 1/C
    const float tg = __builtin_fmaf(2.0f, rGC * C, -1.0f);    // tanh(g2) = 2/G - 1
    const float c2 = __builtin_fmaf(fg, cin, ig * tg);
    const float ec = __builtin_amdgcn_exp2f(-2.0f * LOG2E * c2);
    const float th = __builtin_fmaf(2.0f, __builtin_amdgcn_rcpf(1.0f + ec), -1.0f);
    *cout = c2;
    *hout = og * th;
}

// Merged iteration i (parity P = i&1): P2(i-1) + P1(i) back-to-back.
// Both consume hbuf[P] (h1 post-P1(i-1), x(i), bias): ONE ds_read pair feeds
// all 4 MFMAs. P1 writes h1(i+1) -> hbuf[P^1]; P2 writes part[P^1].
// Emit wave stores out(i-2) from part[P]. One barrier per step.
#define MERGED_BODY(P, EMIT_IDX, DO_EMIT, XI)                                      \
    do {                                                                           \
        if (is_comp) {                                                             \
            const h8 b0 = *(const h8*)&hbuf[P][nl][quad * 8];                      \
            const h8 b1 = *(const h8*)&hbuf[P][nl][32 + quad * 8];                 \
            f4 G1 = {0.f, 0.f, 0.f, 0.f}, G2 = {0.f, 0.f, 0.f, 0.f};               \
            G2 = MFMA(W2[0], b0, G2); G2 = MFMA(W2[1], b1, G2);                    \
            G1 = MFMA(W1[0], b0, G1); G1 = MFMA(W1[1], b1, G1);                    \
            float c2v, h2v;                                                        \
            act_cell(G2, c1, &c2v, &h2v);        /* uses c1 pre-update: P2(i-1) */ \
            float p = h2v * wo;                                                    \
            p += __shfl_xor(p, 16, 64);                                            \
            p += __shfl_xor(p, 32, 64);                                            \
            if (quad == 0) part[(P) ^ 1][cw][nl] = p;                              \
            float hv;                                                              \
            act_cell(G1, c1, &c1, &hv);          /* P1(i): updates c1 */           \
            if (kh < HH) hbuf[(P) ^ 1][nl][1 + kh] = (_Float16)hv;                 \
        } else if (w == we) {                                                      \
            if ((DO_EMIT) && lane < RPB) {                                         \
                float s = bo;                                                      \
                _Pragma("unroll")                                                  \
                for (int j = 0; j < 13; ++j) s += part[P][j][lane];                \
                out[(size_t)(rb + lane) * TT + (EMIT_IDX)] = s;                    \
            }                                                                      \
        } else if (w == wp && lane < RPB) {                                        \
            if ((XI) + 1 < TSEQ) hbuf[(P) ^ 1][lane][0] = (_Float16)xnext;         \
            if ((XI) + 2 < TSEQ) xnext = x[(size_t)(rb + lane) * TSEQ + (XI) + 2]; \
        }                                                                          \
        __syncthreads();                                                           \
    } while (0)

__global__ __launch_bounds__(NTH, 8)
void lstm_kernel(const float* __restrict__ x,
                 const float* __restrict__ Wih1, const float* __restrict__ Whh1,
                 const float* __restrict__ bih1, const float* __restrict__ bhh1,
                 const float* __restrict__ Wih2, const float* __restrict__ Whh2,
                 const float* __restrict__ bih2, const float* __restrict__ bhh2,
                 const float* __restrict__ Wout, const float* __restrict__ bout,
                 float* __restrict__ out)
{
    // double-buffered B-operand: [buf][row][k]; k=0: x_t, 1..51: h1, 52,53: const 1 (bias hi/lo)
    __shared__ _Float16 hbuf[2][RPB][HSTR];
    // per-tile partial sums of wout.h2, double-buffered: [buf][tile][row]
    __shared__ float part[2][13][17];
    __shared__ float wouts[64];

    const int tid  = threadIdx.x;
    const int lane = tid & 63;
    const int w    = tid >> 6;        // physical wave id (SIMD = w & 3)
    const int quad = lane >> 4;       // 0..3
    const int nl   = lane & 15;       // batch row (B-operand n / C-D col)
    const int rb   = blockIdx.x * RPB;

    // Role rotation: 13 compute waves can only split 4-3-3-3 across the 4 SIMDs.
    // Pass-0 blocks (id<256) load SIMD0; pass-1 blocks load SIMD3 -> the two
    // co-resident blocks on a CU balance to ~7/6/6/7 compute waves per SIMD
    // instead of 8/6/6/6 (the saturated SIMD0 was the step-time limiter:
    // VALUBusy 71% == (100+3*62)/4).
    const int  rot     = (blockIdx.x >> 8) & 1;
    const int  cw      = w - (rot ? 3 : 0);     // compute tile id if in [0,13)
    const bool is_comp = (cw >= 0) && (cw < 13);
    const int  we      = rot ? 0 : 13;          // emit wave
    const int  wp      = rot ? 1 : 14;          // x-prefetch wave

    // ---------------- one-time init ----------------
    if (tid < 64) wouts[tid] = (tid < HH) ? Wout[tid] : 0.0f;
    for (int i = tid; i < 2 * RPB * HSTR; i += NTH) (&hbuf[0][0][0])[i] = (_Float16)0.0f;
    __syncthreads();
    if (tid < RPB) {
        hbuf[0][tid][0]  = (_Float16)x[(size_t)(rb + tid) * TSEQ];
        hbuf[0][tid][52] = (_Float16)1.0f;  hbuf[0][tid][53] = (_Float16)1.0f;
        hbuf[1][tid][52] = (_Float16)1.0f;  hbuf[1][tid][53] = (_Float16)1.0f;
    }
    const float bo = bout[0];

    // ---------------- weight A-fragments in registers (once) ----------------
    // compute wave cw owns gate m-tile cw: rows j' = 16cw..16cw+15 (j' = 4k+q interleave)
    h8 W1[2], W2[2];
    if (is_comp) {
        const int jp = 16 * cw + nl;
        const int kk = jp >> 2, q = jp & 3;
        const bool valid = (jp < H4);
        const int jrow = q * HH + kk;        // original gate row
        float b1 = 0.0f, b2 = 0.0f;
        if (valid) { b1 = bih1[jrow] + bhh1[jrow]; b2 = bih2[jrow] + bhh2[jrow]; }
        const _Float16 b1h = (_Float16)b1, b2h = (_Float16)b2;
        const _Float16 b1l = (_Float16)(b1 - (float)b1h), b2l = (_Float16)(b2 - (float)b2h);
        #pragma unroll
        for (int s = 0; s < 2; ++s) {
            h8 w1v, w2v;
            #pragma unroll
            for (int j = 0; j < 8; ++j) {
                const int k = s * 32 + quad * 8 + j;
                _Float16 a1 = (_Float16)0.0f, a2 = (_Float16)0.0f;
                if (valid) {
                    if (k == 0) {
                        a1 = (_Float16)Wih1[jrow];
                    } else if (k <= HH) {
                        const int o = jrow * HH + (k - 1);
                        a1 = (_Float16)Whh1[o];
                        a2 = (_Float16)(Wih2[o] + Whh2[o]);
                    } else if (k == 52) { a1 = b1h; a2 = b2h; }
                    else if (k == 53)   { a1 = b1l; a2 = b2l; }
                }
                w1v[j] = a1;
                w2v[j] = a2;
            }
            W1[s] = w1v;
            W2[s] = w2v;
        }
    }

    // x register pipeline: at merged iteration i, write x(i+1), then load x(i+2)
    float xnext = 0.0f;
    if (w == wp && lane < RPB) xnext = x[(size_t)(rb + lane) * TSEQ + 1];

    const int kh = 4 * cw + quad;     // hidden unit owned by this lane (if is_comp)
    float c1 = 0.0f;
    __syncthreads();
    const float wo = is_comp ? wouts[kh] : 0.0f;

    // ---------------- peel i = 0 : P1(0) only ----------------
    if (is_comp) {
        const h8 b0 = *(const h8*)&hbuf[0][nl][quad * 8];
        const h8 b1 = *(const h8*)&hbuf[0][nl][32 + quad * 8];
        f4 G1 = {0.f, 0.f, 0.f, 0.f};
        G1 = MFMA(W1[0], b0, G1); G1 = MFMA(W1[1], b1, G1);
        float hv;
        act_cell(G1, c1, &c1, &hv);
        if (kh < HH) hbuf[1][nl][1 + kh] = (_Float16)hv;
    } else if (w == wp && lane < RPB) {
        hbuf[1][lane][0] = (_Float16)xnext;               // x(1)
        xnext = x[(size_t)(rb + lane) * TSEQ + 2];        // x(2)
    }
    __syncthreads();

    // ---------------- peel i = 1 : P2(0) + P1(1), nothing to emit yet ----------------
    MERGED_BODY(1, 0, false, 1);

    // ---------------- main: merged iterations i = 2 .. TSEQ-1, unrolled x2 ----------------
    for (int i = 2; i < TSEQ; i += 2) {
        MERGED_BODY(0, i - 2, true, i);
        MERGED_BODY(1, i - 1, true, i + 1);
    }
    // state here: P1 done through t=2047, P2 done through t=2046,
    // out emitted through t=2045; part[0] holds P2(2046).

    // ---------------- FUT tail: t = TSEQ-1 .. TT-1, explicit 3-phase ----------------
    for (int t = TSEQ - 1; t < TT; ++t) {
        const int pb = (t + 1) & 1;   // buffer holding h1(t+1) (+ feedback x slot)
        if (is_comp) {
            // P2(t)
            const h8 b0 = *(const h8*)&hbuf[pb][nl][quad * 8];
            const h8 b1 = *(const h8*)&hbuf[pb][nl][32 + quad * 8];
            f4 G2 = {0.f, 0.f, 0.f, 0.f};
            G2 = MFMA(W2[0], b0, G2); G2 = MFMA(W2[1], b1, G2);
            float c2v, h2v;
            act_cell(G2, c1, &c2v, &h2v);
            float p = h2v * wo;
            p += __shfl_xor(p, 16, 64);
            p += __shfl_xor(p, 32, 64);
            if (quad == 0) part[t & 1][cw][nl] = p;
        } else if (w == we && t == TSEQ - 1 && lane < RPB) {
            // emit out(TSEQ-2) left over from the main loop (part[0] = P2(2046))
            float s = bo;
            #pragma unroll
            for (int j = 0; j < 13; ++j) s += part[0][j][lane];
            out[(size_t)(rb + lane) * TT + (TSEQ - 2)] = s;
        }
        __syncthreads();
        if (w == we && lane < RPB) {
            float s = bo;
            #pragma unroll
            for (int j = 0; j < 13; ++j) s += part[t & 1][j][lane];
            out[(size_t)(rb + lane) * TT + t] = s;
            if (t + 1 < TT) hbuf[pb][lane][0] = (_Float16)s;   // autoregressive x(t+1)
        }
        __syncthreads();
        if (t + 1 < TT) {
            if (is_comp) {
                // P1(t+1): reads hbuf[pb] (h1(t+1) + feedback x), writes h1(t+2)
                const h8 b0 = *(const h8*)&hbuf[pb][nl][quad * 8];
                const h8 b1 = *(const h8*)&hbuf[pb][nl][32 + quad * 8];
                f4 G1 = {0.f, 0.f, 0.f, 0.f};
                G1 = MFMA(W1[0], b0, G1); G1 = MFMA(W1[1], b1, G1);
                float hv;
                act_cell(G1, c1, &c1, &hv);
                if (kh < HH) hbuf[pb ^ 1][nl][1 + kh] = (_Float16)hv;
            }
            __syncthreads();
        }
    }
}

extern "C" void kernel_launch(void* const* d_in, const int* in_sizes, int n_in,
                              void* d_out, int out_size, void* d_ws, size_t ws_size,
                              hipStream_t stream) {
    (void)in_sizes; (void)n_in; (void)d_ws; (void)ws_size; (void)out_size;
    const float* x    = (const float*)d_in[0];
    const float* Wih1 = (const float*)d_in[1];
    const float* Whh1 = (const float*)d_in[2];
    const float* bih1 = (const float*)d_in[3];
    const float* bhh1 = (const float*)d_in[4];
    const float* Wih2 = (const float*)d_in[5];
    const float* Whh2 = (const float*)d_in[6];
    const float* bih2 = (const float*)d_in[7];
    const float* bhh2 = (const float*)d_in[8];
    const float* Wout = (const float*)d_in[9];
    const float* bout = (const float*)d_in[10];
    float* outp = (float*)d_out;

    dim3 grid(8192 / RPB);   // 512 blocks, 2 per CU
    dim3 block(NTH);
    hipLaunchKernelGGL(lstm_kernel, grid, block, 0, stream,
                       x, Wih1, Whh1, bih1, bhh1, Wih2, Whh2, bih2, bhh2,
                       Wout, bout, outp);
}

// Round 2
// 2502.349 us; speedup vs baseline: 1.1835x; 1.1063x over previous
//
#include <hip/hip_runtime.h>

#define HH   51
#define H4   204
#define TSEQ 2048
#define FUT  64
#define TT   (TSEQ + FUT)   // 2112
#define RPB  16             // batch rows per block (2 blocks/CU)
#define NTH  1024           // 16 waves: 13 compute + emit + x-prefetch + 1 idle
#define HSTR 72             // halfs per hbuf row (144 B stride: 16B-aligned, 2-way max conflict)

typedef _Float16 h8 __attribute__((ext_vector_type(8)));
typedef float    f4 __attribute__((ext_vector_type(4)));

#define LOG2E 1.44269504f
#define MFMA(a, b, c) __builtin_amdgcn_mfma_f32_16x16x32_f16(a, b, c, 0, 0, 0)

// LSTM-cell nonlinearity from PRE-SCALED gate pre-activations:
//   g[0] = -log2e * z_i, g[1] = -log2e * z_f, g[2] = -2 log2e * z_g, g[3] = -log2e * z_o
// (scales folded into the f16 A-fragments/biases at weight-load time), so the
// four exp2 args need no multiplies. Pairwise-reciprocal: 5 exp2 + 3 rcp.
__device__ __forceinline__ void act_cell(const f4 g, float cin, float* cout, float* hout) {
    const float ei = __builtin_amdgcn_exp2f(g[0]);
    const float ef = __builtin_amdgcn_exp2f(g[1]);
    const float eg = __builtin_amdgcn_exp2f(g[2]);
    const float eo = __builtin_amdgcn_exp2f(g[3]);
    const float A = 1.0f + ei, B = 1.0f + ef, G = 1.0f + eg, C = 1.0f + eo;
    const float rAB = __builtin_amdgcn_rcpf(A * B);
    const float ig = rAB * B;                                 // sigmoid(z_i) = 1/A
    const float fg = rAB * A;                                 // sigmoid(z_f) = 1/B
    const float rGC = __builtin_amdgcn_rcpf(G * C);
    const float og = rGC * G;                                 // sigmoid(z_o) = 1/C
    const float tg = __builtin_fmaf(2.0f, rGC * C, -1.0f);    // tanh(z_g) = 2/G - 1
    const float c2 = __builtin_fmaf(fg, cin, ig * tg);
    const float ec = __builtin_amdgcn_exp2f(-2.0f * LOG2E * c2);
    const float th = __builtin_fmaf(2.0f, __builtin_amdgcn_rcpf(1.0f + ec), -1.0f);
    *cout = c2;
    *hout = og * th;
}

// Merged iteration i (parity P = i&1): P2(i-1) + P1(i) back-to-back.
// Both consume hbuf[P]: ONE ds_read pair feeds all 4 MFMAs. P1 writes h1(i+1)
// -> hbuf[P^1]; P2 writes its weighted h2 partial DIRECTLY to part[P^1] (all
// 64 lanes, no cross-lane shuffle chain); emit wave sums 13x4 partials for
// out(i-2) from part[P]. One barrier per step.
#define MERGED_BODY(P, EMIT_IDX, DO_EMIT, XI)                                      \
    do {                                                                           \
        if (is_comp) {                                                             \
            const h8 b0 = *(const h8*)&hbuf[P][nl][quad * 8];                      \
            const h8 b1 = *(const h8*)&hbuf[P][nl][32 + quad * 8];                 \
            f4 G1 = {0.f, 0.f, 0.f, 0.f}, G2 = {0.f, 0.f, 0.f, 0.f};               \
            G2 = MFMA(W2[0], b0, G2); G2 = MFMA(W2[1], b1, G2);                    \
            G1 = MFMA(W1[0], b0, G1); G1 = MFMA(W1[1], b1, G1);                    \
            float c2v, h2v;                                                        \
            act_cell(G2, c1, &c2v, &h2v);        /* uses c1 pre-update: P2(i-1) */ \
            part[(P) ^ 1][cw][quad][nl] = h2v * wo;                                \
            float hv;                                                              \
            act_cell(G1, c1, &c1, &hv);          /* P1(i): updates c1 */           \
            if (kh < HH) hbuf[(P) ^ 1][nl][1 + kh] = (_Float16)hv;                 \
        } else if (w == we) {                                                      \
            if ((DO_EMIT) && lane < RPB) {                                         \
                float s0 = bo, s1 = 0.f, s2 = 0.f, s3 = 0.f;                       \
                _Pragma("unroll")                                                  \
                for (int j = 0; j < 13; ++j) {                                     \
                    s0 += part[P][j][0][lane];                                     \
                    s1 += part[P][j][1][lane];                                     \
                    s2 += part[P][j][2][lane];                                     \
                    s3 += part[P][j][3][lane];                                     \
                }                                                                  \
                out[(size_t)(rb + lane) * TT + (EMIT_IDX)] = (s0 + s1) + (s2 + s3);\
            }                                                                      \
        } else if (w == wp && lane < RPB) {                                        \
            if ((XI) + 1 < TSEQ) hbuf[(P) ^ 1][lane][0] = (_Float16)xnext;         \
            if ((XI) + 2 < TSEQ) xnext = x[(size_t)(rb + lane) * TSEQ + (XI) + 2]; \
        }                                                                          \
        __syncthreads();                                                           \
    } while (0)

__global__ __launch_bounds__(NTH, 8)
void lstm_kernel(const float* __restrict__ x,
                 const float* __restrict__ Wih1, const float* __restrict__ Whh1,
                 const float* __restrict__ bih1, const float* __restrict__ bhh1,
                 const float* __restrict__ Wih2, const float* __restrict__ Whh2,
                 const float* __restrict__ bih2, const float* __restrict__ bhh2,
                 const float* __restrict__ Wout, const float* __restrict__ bout,
                 float* __restrict__ out)
{
    // double-buffered B-operand: [buf][row][k]; k=0: x_t, 1..51: h1, 52,53: const 1 (bias hi/lo)
    __shared__ _Float16 hbuf[2][RPB][HSTR];
    // per-(tile,quad) partials of wout.h2, double-buffered: [buf][tile][quad][row]
    __shared__ float part[2][13][4][17];
    __shared__ float wouts[64];

    const int tid  = threadIdx.x;
    const int lane = tid & 63;
    const int w    = tid >> 6;        // physical wave id (SIMD = w & 3)
    const int quad = lane >> 4;       // 0..3
    const int nl   = lane & 15;       // batch row (B-operand n / C-D col)
    const int rb   = blockIdx.x * RPB;

    // Role rotation: 13 compute waves split 4-3-3-3 over SIMDs; pass-0 blocks
    // load SIMD0, pass-1 blocks load SIMD3 -> co-resident blocks balance to
    // ~7/6/6/7 compute waves per SIMD.
    const int  rot     = (blockIdx.x >> 8) & 1;
    const int  cw      = w - (rot ? 3 : 0);     // compute tile id if in [0,13)
    const bool is_comp = (cw >= 0) && (cw < 13);
    const int  we      = rot ? 0 : 13;          // emit wave
    const int  wp      = rot ? 1 : 14;          // x-prefetch wave

    // ---------------- one-time init ----------------
    if (tid < 64) wouts[tid] = (tid < HH) ? Wout[tid] : 0.0f;
    for (int i = tid; i < 2 * RPB * HSTR; i += NTH) (&hbuf[0][0][0])[i] = (_Float16)0.0f;
    __syncthreads();
    if (tid < RPB) {
        hbuf[0][tid][0]  = (_Float16)x[(size_t)(rb + tid) * TSEQ];
        hbuf[0][tid][52] = (_Float16)1.0f;  hbuf[0][tid][53] = (_Float16)1.0f;
        hbuf[1][tid][52] = (_Float16)1.0f;  hbuf[1][tid][53] = (_Float16)1.0f;
    }
    const float bo = bout[0];

    // ---------------- weight A-fragments in registers (once) ----------------
    // compute wave cw owns gate m-tile cw: rows j' = 16cw..16cw+15 (j' = 4k+q interleave)
    // Gate rows pre-scaled so MFMA emits exp2-ready args: i,f,o by -log2e, g by -2 log2e.
    h8 W1[2], W2[2];
    if (is_comp) {
        const int jp = 16 * cw + nl;
        const int kk = jp >> 2, q = jp & 3;
        const bool valid = (jp < H4);
        const int jrow = q * HH + kk;        // original gate row
        const float sc = (q == 2) ? (-2.0f * LOG2E) : (-LOG2E);
        float b1 = 0.0f, b2 = 0.0f;
        if (valid) { b1 = sc * (bih1[jrow] + bhh1[jrow]); b2 = sc * (bih2[jrow] + bhh2[jrow]); }
        const _Float16 b1h = (_Float16)b1, b2h = (_Float16)b2;
        const _Float16 b1l = (_Float16)(b1 - (float)b1h), b2l = (_Float16)(b2 - (float)b2h);
        #pragma unroll
        for (int s = 0; s < 2; ++s) {
            h8 w1v, w2v;
            #pragma unroll
            for (int j = 0; j < 8; ++j) {
                const int k = s * 32 + quad * 8 + j;
                _Float16 a1 = (_Float16)0.0f, a2 = (_Float16)0.0f;
                if (valid) {
                    if (k == 0) {
                        a1 = (_Float16)(sc * Wih1[jrow]);
                    } else if (k <= HH) {
                        const int o = jrow * HH + (k - 1);
                        a1 = (_Float16)(sc * Whh1[o]);
                        a2 = (_Float16)(sc * (Wih2[o] + Whh2[o]));
                    } else if (k == 52) { a1 = b1h; a2 = b2h; }
                    else if (k == 53)   { a1 = b1l; a2 = b2l; }
                }
                w1v[j] = a1;
                w2v[j] = a2;
            }
            W1[s] = w1v;
            W2[s] = w2v;
        }
    }

    // x register pipeline: at merged iteration i, write x(i+1), then load x(i+2)
    float xnext = 0.0f;
    if (w == wp && lane < RPB) xnext = x[(size_t)(rb + lane) * TSEQ + 1];

    const int kh = 4 * cw + quad;     // hidden unit owned by this lane (if is_comp)
    float c1 = 0.0f;
    __syncthreads();
    const float wo = is_comp ? wouts[kh] : 0.0f;

    // ---------------- peel i = 0 : P1(0) only ----------------
    if (is_comp) {
        const h8 b0 = *(const h8*)&hbuf[0][nl][quad * 8];
        const h8 b1 = *(const h8*)&hbuf[0][nl][32 + quad * 8];
        f4 G1 = {0.f, 0.f, 0.f, 0.f};
        G1 = MFMA(W1[0], b0, G1); G1 = MFMA(W1[1], b1, G1);
        float hv;
        act_cell(G1, c1, &c1, &hv);
        if (kh < HH) hbuf[1][nl][1 + kh] = (_Float16)hv;
    } else if (w == wp && lane < RPB) {
        hbuf[1][lane][0] = (_Float16)xnext;               // x(1)
        xnext = x[(size_t)(rb + lane) * TSEQ + 2];        // x(2)
    }
    __syncthreads();

    // ---------------- peel i = 1 : P2(0) + P1(1), nothing to emit yet ----------------
    MERGED_BODY(1, 0, false, 1);

    // ---------------- main: merged iterations i = 2 .. TSEQ-1, unrolled x2 ----------------
    for (int i = 2; i < TSEQ; i += 2) {
        MERGED_BODY(0, i - 2, true, i);
        MERGED_BODY(1, i - 1, true, i + 1);
    }
    // state here: P1 done through t=2047, P2 done through t=2046,
    // out emitted through t=2045; part[0] holds P2(2046).

    // ---------------- FUT tail: t = TSEQ-1 .. TT-1, explicit 3-phase ----------------
    for (int t = TSEQ - 1; t < TT; ++t) {
        const int pb = (t + 1) & 1;   // buffer holding h1(t+1) (+ feedback x slot)
        if (is_comp) {
            // P2(t)
            const h8 b0 = *(const h8*)&hbuf[pb][nl][quad * 8];
            const h8 b1 = *(const h8*)&hbuf[pb][nl][32 + quad * 8];
            f4 G2 = {0.f, 0.f, 0.f, 0.f};
            G2 = MFMA(W2[0], b0, G2); G2 = MFMA(W2[1], b1, G2);
            float c2v, h2v;
            act_cell(G2, c1, &c2v, &h2v);
            part[t & 1][cw][quad][nl] = h2v * wo;
        } else if (w == we && t == TSEQ - 1 && lane < RPB) {
            // emit out(TSEQ-2) left over from the main loop (part[0] = P2(2046))
            float s0 = bo, s1 = 0.f, s2 = 0.f, s3 = 0.f;
            #pragma unroll
            for (int j = 0; j < 13; ++j) {
                s0 += part[0][j][0][lane];
                s1 += part[0][j][1][lane];
                s2 += part[0][j][2][lane];
                s3 += part[0][j][3][lane];
            }
            out[(size_t)(rb + lane) * TT + (TSEQ - 2)] = (s0 + s1) + (s2 + s3);
        }
        __syncthreads();
        if (w == we && lane < RPB) {
            float s0 = bo, s1 = 0.f, s2 = 0.f, s3 = 0.f;
            #pragma unroll
            for (int j = 0; j < 13; ++j) {
                s0 += part[t & 1][j][0][lane];
                s1 += part[t & 1][j][1][lane];
                s2 += part[t & 1][j][2][lane];
                s3 += part[t & 1][j][3][lane];
            }
            const float s = (s0 + s1) + (s2 + s3);
            out[(size_t)(rb + lane) * TT + t] = s;
            if (t + 1 < TT) hbuf[pb][lane][0] = (_Float16)s;   // autoregressive x(t+1)
        }
        __syncthreads();
        if (t + 1 < TT) {
            if (is_comp) {
                // P1(t+1): reads hbuf[pb] (h1(t+1) + feedback x), writes h1(t+2)
                const h8 b0 = *(const h8*)&hbuf[pb][nl][quad * 8];
                const h8 b1 = *(const h8*)&hbuf[pb][nl][32 + quad * 8];
                f4 G1 = {0.f, 0.f, 0.f, 0.f};
                G1 = MFMA(W1[0], b0, G1); G1 = MFMA(W1[1], b1, G1);
                float hv;
                act_cell(G1, c1, &c1, &hv);
                if (kh < HH) hbuf[pb ^ 1][nl][1 + kh] = (_Float16)hv;
            }
            __syncthreads();
        }
    }
}

extern "C" void kernel_launch(void* const* d_in, const int* in_sizes, int n_in,
                              void* d_out, int out_size, void* d_ws, size_t ws_size,
                              hipStream_t stream) {
    (void)in_sizes; (void)n_in; (void)d_ws; (void)ws_size; (void)out_size;
    const float* x    = (const float*)d_in[0];
    const float* Wih1 = (const float*)d_in[1];
    const float* Whh1 = (const float*)d_in[2];
    const float* bih1 = (const float*)d_in[3];
    const float* bhh1 = (const float*)d_in[4];
    const float* Wih2 = (const float*)d_in[5];
    const float* Whh2 = (const float*)d_in[6];
    const float* bih2 = (const float*)d_in[7];
    const float* bhh2 = (const float*)d_in[8];
    const float* Wout = (const float*)d_in[9];
    const float* bout = (const float*)d_in[10];
    float* outp = (float*)d_out;

    dim3 grid(8192 / RPB);   // 512 blocks, 2 per CU
    dim3 block(NTH);
    hipLaunchKernelGGL(lstm_kernel, grid, block, 0, stream,
                       x, Wih1, Whh1, bih1, bhh1, Wih2, Whh2, bih2, bhh2,
                       Wout, bout, outp);
}